// Round 5
// baseline (319.378 us; speedup 1.0000x reference)
//
#include <hip/hip_runtime.h>
#include <hip/hip_cooperative_groups.h>
#include <math.h>

namespace cg = cooperative_groups;

// SoftKConv, round 18 (= r15/r16/r17 resubmitted; all prior benches died on
// GPU acquisition timeout — no data, kernel still untested on HW).
// r14 post-mortem: 3 waves/WG changed NOTHING (occ 34->32, softk 63.8us).
// Wave residency is pinned ~10.5/CU regardless of block packing; no pipe
// >50%. Bigger anomaly: total dur 152.7us vs softk 63us + gemm <~6us +
// prep ~1us => ~85us lives BETWEEN kernels (launch gaps / harness resets).
// r15..r18: single cooperative kernel, prep + gemm + softk separated by two
// grid.sync()s. Phase math bit-identical to r14. Grid sized via the
// occupancy API (expected ~5 blk/CU x 3 waves = 15 waves/CU, also above
// today's ~10.5). Non-cooperative 3-kernel fallback if coop launch fails.

typedef __attribute__((ext_vector_type(2)))  _Float16 half2v;
typedef __attribute__((ext_vector_type(4)))  _Float16 half4v;
typedef __attribute__((ext_vector_type(8)))  _Float16 half8;
typedef __attribute__((ext_vector_type(16))) float    f32x16;

#define NK   32
#define DIM  128
// LDS row stride 272 B (64 dwords used + 4 pad); rotation 16*(k&3) dwords.
#define ROWB 272
// waves (independent node streams) per workgroup
#define WPB  3

// ========================= fused cooperative kernel ========================
__global__ __launch_bounds__(192, 4) void fused(
    const float* __restrict__ feat, const float* __restrict__ W,
    const float* __restrict__ bias, const float* __restrict__ tkw,
    const int* __restrict__ idx, float* __restrict__ out,
    _Float16* __restrict__ hq, _Float16* __restrict__ wt, int n)
{
    cg::grid_group gg = cg::this_grid();

    __shared__ __align__(16) char  fkT[WPB][NK * ROWB];   // 3 x 8704 B
    __shared__ __align__(16) float rbuf[WPB][NK];         // 3 x  128 B

    const int w    = threadIdx.x >> 6;   // wave id in block, 0..2
    const int lane = threadIdx.x & 63;
    const int l31  = lane & 31;
    const int hf   = lane >> 5;

    // ---------------- phase 0: WT[n][k] = (f16) W[k][n] --------------------
    {
        int t0 = blockIdx.x * 192 + threadIdx.x;
        if (t0 < DIM * DIM) {
            int nn = t0 >> 7, k = t0 & 127;
            wt[t0] = (_Float16)W[k * 128 + nn];
        }
    }
    gg.sync();

    // ---------------- phase 1: hq = f16(feat @ W), MFMA --------------------
    {
        const int nwaves = gridDim.x * WPB;
        const int gw     = blockIdx.x * WPB + w;
        const int ntiles = (n + 31) >> 5;
        for (int tile = gw; tile < ntiles; tile += nwaves) {
            const int row  = tile * 32 + l31;
            const int rowc = row < n ? row : n - 1;

            f32x16 gacc[4];
#pragma unroll
            for (int t = 0; t < 4; ++t)
#pragma unroll
                for (int i = 0; i < 16; ++i) gacc[t][i] = 0.0f;

            const float* ap = feat + (size_t)rowc * 128 + 8 * hf;
#pragma unroll
            for (int s = 0; s < 8; ++s) {
                float4 b0 = *reinterpret_cast<const float4*>(ap + 16 * s);
                float4 b1 = *reinterpret_cast<const float4*>(ap + 16 * s + 4);
                half8 bf;
                bf[0] = (_Float16)b0.x; bf[1] = (_Float16)b0.y;
                bf[2] = (_Float16)b0.z; bf[3] = (_Float16)b0.w;
                bf[4] = (_Float16)b1.x; bf[5] = (_Float16)b1.y;
                bf[6] = (_Float16)b1.z; bf[7] = (_Float16)b1.w;
#pragma unroll
                for (int t = 0; t < 4; ++t) {
                    half8 af = *reinterpret_cast<const half8*>(
                        wt + (size_t)(l31 + 32 * t) * 128 + 16 * s + 8 * hf);
                    gacc[t] = __builtin_amdgcn_mfma_f32_32x32x16_f16(af, bf, gacc[t], 0, 0, 0);
                }
            }

            if (row < n) {
                _Float16* hp = hq + (size_t)row * 128;
#pragma unroll
                for (int t = 0; t < 4; ++t)
#pragma unroll
                    for (int gq = 0; gq < 4; ++gq) {
                        half4v hv;
#pragma unroll
                        for (int q = 0; q < 4; ++q) hv[q] = (_Float16)gacc[t][4 * gq + q];
                        *reinterpret_cast<half4v*>(hp + 32 * t + 8 * gq + 4 * hf) = hv;
                    }
            }
        }
    }
    gg.sync();

    // ---------------- phase 2: per-node soft medoid, pipelined -------------
    {
        const int g    = lane >> 4;        // gather row group 0..3
        const int m    = lane & 15;        // gather 16B chunk 0..15
        const int pbase = (lane & 32) + ((lane & 32) >> 3);

        char* fkw = &fkT[w][0];

        // loop-invariant addresses
        const int d0 = 2 * lane;
        const float2 bv = *reinterpret_cast<const float2*>(bias + d0);
        const float4* rb = reinterpret_cast<const float4*>(&rbuf[w][0]);
        const int wbase = ROWB * g + 16 * ((m + 4 * g) & 15);
        const int fbase = ROWB * l31;
        const int uc0   = 4 * hf + 16 * (l31 & 3);       // dword col bias
        int eaddr[4];
#pragma unroll
        for (int p = 0; p < 4; ++p) eaddr[p] = 4 * ((lane + 16 * p) & 63);

        const int stride = gridDim.x * WPB;
        int nd = blockIdx.x * WPB + w;
        if (nd >= n) return;

        // ---- prologue: first node's idx/tkw + coalesced gather ----
        int   vid = idx[(size_t)nd * NK + l31];
        float tw  = tkw[(size_t)nd * NK + l31];
        int   mkc = (vid < 0) ? 1 : 0;
        float wc  = mkc ? 0.0f : tw;
        half8 gb[8];
        {
            int idr = mkc ? 0 : vid;
#pragma unroll
            for (int i = 0; i < 8; ++i) {
                int idg = __shfl(idr, 4 * i + g, 64);
                gb[i] = *reinterpret_cast<const half8*>(
                    hq + (size_t)idg * DIM + 8 * m);
            }
        }

        while (true) {
            const int  ndn = nd + stride;
            const bool hn  = ndn < n;

            // pipeline stage 1: next node's idx/tkw
            int vid_n = 0; float tw_n = 0.0f;
            if (hn) {
                vid_n = idx[(size_t)ndn * NK + l31];
                tw_n  = tkw[(size_t)ndn * NK + l31];
            }

            // ---- coalesced write of gathered rows into rotated LDS ----
#pragma unroll
            for (int i = 0; i < 8; ++i)
                *reinterpret_cast<half8*>(&fkw[1088 * i + wbase]) = gb[i];

            // ---- frag reads (row l31, rotated) + gram MFMA + fdot2 sq ----
            f32x16 acc;
#pragma unroll
            for (int i = 0; i < 16; ++i) acc[i] = 0.0f;
            float sqp = 0.0f;
            int u = uc0;
#pragma unroll
            for (int s = 0; s < 8; ++s) {
                half8 fr = *reinterpret_cast<const half8*>(&fkw[fbase + 4 * (u & 63)]);
                u += 8;
                acc = __builtin_amdgcn_mfma_f32_32x32x16_f16(fr, fr, acc, 0, 0, 0);
                const half2v* p2 = reinterpret_cast<const half2v*>(&fr);
#pragma unroll
                for (int q = 0; q < 4; ++q)
                    sqp = __builtin_amdgcn_fdot2(p2[q], p2[q], sqp, false);
            }
            float sq = sqp + __shfl_xor(sqp, 32, 64);

            // pipeline stage 2: next node's coalesced gather
            const int mk_n = (vid_n < 0) ? 1 : 0;
            half8 gb_n[8];
            if (hn) {
                int idr_n = mk_n ? 0 : vid_n;
#pragma unroll
                for (int i = 0; i < 8; ++i) {
                    int idg = __shfl(idr_n, 4 * i + g, 64);
                    gb_n[i] = *reinterpret_cast<const half8*>(
                        hq + (size_t)idg * DIM + 8 * m);
                }
            }

            // 9th MFMA: acc += -(sq_m + sq_c)/2 -> acc = -d2/2
            {
                _Float16 shi = (_Float16)sq;
                _Float16 slo = (_Float16)(sq - (float)shi);
                _Float16 nh  = (_Float16)(-0.5f * (float)shi);
                _Float16 nl  = (_Float16)(-0.5f * (float)slo);
                _Float16 z   = (_Float16)0.0f, one = (_Float16)1.0f;
                half8 aext = {z, z, z, z, z, z, z, z};
                half8 bext = {z, z, z, z, z, z, z, z};
                if (hf == 0) {
                    aext[0] = nh;  aext[1] = nl;  aext[2] = one; aext[3] = one;
                    bext[0] = one; bext[1] = one; bext[2] = nh;  bext[3] = nl;
                }
                acc = __builtin_amdgcn_mfma_f32_32x32x16_f16(aext, bext, acc, 0, 0, 0);
            }

            // dagg[c=l31] = sum_m w[m]*dist[m][c]
            float pt[4] = {0.0f, 0.0f, 0.0f, 0.0f};
#pragma unroll
            for (int reg = 0; reg < 16; ++reg) {
                const int c = (reg & 3) + 8 * (reg >> 2);
                float wr = __shfl(wc, pbase + c, 64);
                float d2 = fmaxf(-(acc[reg] + acc[reg]), 0.0f);
                float ds = (d2 > 1e-4f) ? __builtin_amdgcn_sqrtf(d2) : 0.0f;
                pt[reg & 3] = fmaf(wr, ds, pt[reg & 3]);
            }
            float part = (pt[0] + pt[1]) + (pt[2] + pt[3]);
            float sA = part + __shfl_xor(part, 32, 64);
            if (mkc || !(sA < 3.4028235e38f)) sA = 3.4028235e38f;

            // fused softmax + weight correction: r = e*w / sum(e*w)
            float x  = -sA;
            float mx = x;
#pragma unroll
            for (int o = 16; o > 0; o >>= 1) mx = fmaxf(mx, __shfl_xor(mx, o, 32));
            float tt = __expf(x - mx) * wc;
            float st = tt;
#pragma unroll
            for (int o = 16; o > 0; o >>= 1) st += __shfl_xor(st, o, 32);
            float r = tt * __builtin_amdgcn_rcpf(st);

            rbuf[w][l31] = r;

            // ---- epilogue: out[d] = sum_k r_k * fk[k][d]; 2 dims/lane ----
            float o0 = 0.0f, o1 = 0.0f;
#pragma unroll
            for (int q = 0; q < 8; ++q) {
                float4 rv = rb[q];
                half2v h0 = *reinterpret_cast<const half2v*>(&fkw[ROWB * (4 * q + 0) + eaddr[0]]);
                half2v h1 = *reinterpret_cast<const half2v*>(&fkw[ROWB * (4 * q + 1) + eaddr[1]]);
                half2v h2 = *reinterpret_cast<const half2v*>(&fkw[ROWB * (4 * q + 2) + eaddr[2]]);
                half2v h3 = *reinterpret_cast<const half2v*>(&fkw[ROWB * (4 * q + 3) + eaddr[3]]);
                o0 = fmaf(rv.x, (float)h0[0], o0); o1 = fmaf(rv.x, (float)h0[1], o1);
                o0 = fmaf(rv.y, (float)h1[0], o0); o1 = fmaf(rv.y, (float)h1[1], o1);
                o0 = fmaf(rv.z, (float)h2[0], o0); o1 = fmaf(rv.z, (float)h2[1], o1);
                o0 = fmaf(rv.w, (float)h3[0], o0); o1 = fmaf(rv.w, (float)h3[1], o1);
            }
            float2 ov = { o0 + bv.x, o1 + bv.y };
            *reinterpret_cast<float2*>(out + (size_t)nd * DIM + d0) = ov;

            if (!hn) break;
            nd  = ndn;
            mkc = mk_n;
            wc  = mk_n ? 0.0f : tw_n;
#pragma unroll
            for (int i = 0; i < 8; ++i) gb[i] = gb_n[i];
        }
    }
}

// ===================== fallback: original 3-kernel path =====================
__global__ __launch_bounds__(256) void prep(const float* __restrict__ W,
                                            _Float16* __restrict__ WT) {
    int t  = blockIdx.x * 256 + threadIdx.x;
    int nn = t >> 7, k = t & 127;
    WT[t] = (_Float16)W[k * 128 + nn];
}

__global__ __launch_bounds__(64) void gemm128(
    const float* __restrict__ A, const _Float16* __restrict__ WT,
    _Float16* __restrict__ Hq, int n)
{
    const int lane = threadIdx.x;
    const int l31  = lane & 31;
    const int hf   = lane >> 5;

    const int row  = blockIdx.x * 32 + l31;
    const int rowc = row < n ? row : n - 1;

    f32x16 acc[4];
#pragma unroll
    for (int t = 0; t < 4; ++t)
#pragma unroll
        for (int i = 0; i < 16; ++i) acc[t][i] = 0.0f;

    const float* ap = A + (size_t)rowc * 128 + 8 * hf;
#pragma unroll
    for (int s = 0; s < 8; ++s) {
        float4 b0 = *reinterpret_cast<const float4*>(ap + 16 * s);
        float4 b1 = *reinterpret_cast<const float4*>(ap + 16 * s + 4);
        half8 bf;
        bf[0] = (_Float16)b0.x; bf[1] = (_Float16)b0.y;
        bf[2] = (_Float16)b0.z; bf[3] = (_Float16)b0.w;
        bf[4] = (_Float16)b1.x; bf[5] = (_Float16)b1.y;
        bf[6] = (_Float16)b1.z; bf[7] = (_Float16)b1.w;
#pragma unroll
        for (int t = 0; t < 4; ++t) {
            half8 af = *reinterpret_cast<const half8*>(
                WT + (size_t)(l31 + 32 * t) * 128 + 16 * s + 8 * hf);
            acc[t] = __builtin_amdgcn_mfma_f32_32x32x16_f16(af, bf, acc[t], 0, 0, 0);
        }
    }

    if (row < n) {
        _Float16* hp = Hq + (size_t)row * 128;
#pragma unroll
        for (int t = 0; t < 4; ++t)
#pragma unroll
            for (int g = 0; g < 4; ++g) {
                half4v hv;
#pragma unroll
                for (int q = 0; q < 4; ++q) hv[q] = (_Float16)acc[t][4 * g + q];
                *reinterpret_cast<half4v*>(hp + 32 * t + 8 * g + 4 * hf) = hv;
            }
    }
}

__global__ __launch_bounds__(192, 4) void softk(
    const _Float16* __restrict__ hq, const float* __restrict__ bias,
    const float* __restrict__ tkw, const int* __restrict__ idx,
    float* __restrict__ out, int n)
{
    __shared__ __align__(16) char  fkT[WPB][NK * ROWB];
    __shared__ __align__(16) float rbuf[WPB][NK];

    const int w    = threadIdx.x >> 6;
    const int lane = threadIdx.x & 63;
    const int l31  = lane & 31;
    const int hf   = lane >> 5;
    const int g    = lane >> 4;
    const int m    = lane & 15;
    const int pbase = (lane & 32) + ((lane & 32) >> 3);

    char* fkw = &fkT[w][0];

    const int d0 = 2 * lane;
    const float2 bv = *reinterpret_cast<const float2*>(bias + d0);
    const float4* rb = reinterpret_cast<const float4*>(&rbuf[w][0]);
    const int wbase = ROWB * g + 16 * ((m + 4 * g) & 15);
    const int fbase = ROWB * l31;
    const int uc0   = 4 * hf + 16 * (l31 & 3);
    int eaddr[4];
#pragma unroll
    for (int p = 0; p < 4; ++p) eaddr[p] = 4 * ((lane + 16 * p) & 63);

    const int stride = gridDim.x * WPB;
    int nd = blockIdx.x * WPB + w;
    if (nd >= n) return;

    int   vid = idx[(size_t)nd * NK + l31];
    float tw  = tkw[(size_t)nd * NK + l31];
    int   mkc = (vid < 0) ? 1 : 0;
    float wc  = mkc ? 0.0f : tw;
    half8 gb[8];
    {
        int idr = mkc ? 0 : vid;
#pragma unroll
        for (int i = 0; i < 8; ++i) {
            int idg = __shfl(idr, 4 * i + g, 64);
            gb[i] = *reinterpret_cast<const half8*>(
                hq + (size_t)idg * DIM + 8 * m);
        }
    }

    while (true) {
        const int  ndn = nd + stride;
        const bool hn  = ndn < n;

        int vid_n = 0; float tw_n = 0.0f;
        if (hn) {
            vid_n = idx[(size_t)ndn * NK + l31];
            tw_n  = tkw[(size_t)ndn * NK + l31];
        }

#pragma unroll
        for (int i = 0; i < 8; ++i)
            *reinterpret_cast<half8*>(&fkw[1088 * i + wbase]) = gb[i];

        f32x16 acc;
#pragma unroll
        for (int i = 0; i < 16; ++i) acc[i] = 0.0f;
        float sqp = 0.0f;
        int u = uc0;
#pragma unroll
        for (int s = 0; s < 8; ++s) {
            half8 fr = *reinterpret_cast<const half8*>(&fkw[fbase + 4 * (u & 63)]);
            u += 8;
            acc = __builtin_amdgcn_mfma_f32_32x32x16_f16(fr, fr, acc, 0, 0, 0);
            const half2v* p2 = reinterpret_cast<const half2v*>(&fr);
#pragma unroll
            for (int q = 0; q < 4; ++q)
                sqp = __builtin_amdgcn_fdot2(p2[q], p2[q], sqp, false);
        }
        float sq = sqp + __shfl_xor(sqp, 32, 64);

        const int mk_n = (vid_n < 0) ? 1 : 0;
        half8 gb_n[8];
        if (hn) {
            int idr_n = mk_n ? 0 : vid_n;
#pragma unroll
            for (int i = 0; i < 8; ++i) {
                int idg = __shfl(idr_n, 4 * i + g, 64);
                gb_n[i] = *reinterpret_cast<const half8*>(
                    hq + (size_t)idg * DIM + 8 * m);
            }
        }

        {
            _Float16 shi = (_Float16)sq;
            _Float16 slo = (_Float16)(sq - (float)shi);
            _Float16 nh  = (_Float16)(-0.5f * (float)shi);
            _Float16 nl  = (_Float16)(-0.5f * (float)slo);
            _Float16 z   = (_Float16)0.0f, one = (_Float16)1.0f;
            half8 aext = {z, z, z, z, z, z, z, z};
            half8 bext = {z, z, z, z, z, z, z, z};
            if (hf == 0) {
                aext[0] = nh;  aext[1] = nl;  aext[2] = one; aext[3] = one;
                bext[0] = one; bext[1] = one; bext[2] = nh;  bext[3] = nl;
            }
            acc = __builtin_amdgcn_mfma_f32_32x32x16_f16(aext, bext, acc, 0, 0, 0);
        }

        float pt[4] = {0.0f, 0.0f, 0.0f, 0.0f};
#pragma unroll
        for (int reg = 0; reg < 16; ++reg) {
            const int c = (reg & 3) + 8 * (reg >> 2);
            float wr = __shfl(wc, pbase + c, 64);
            float d2 = fmaxf(-(acc[reg] + acc[reg]), 0.0f);
            float ds = (d2 > 1e-4f) ? __builtin_amdgcn_sqrtf(d2) : 0.0f;
            pt[reg & 3] = fmaf(wr, ds, pt[reg & 3]);
        }
        float part = (pt[0] + pt[1]) + (pt[2] + pt[3]);
        float sA = part + __shfl_xor(part, 32, 64);
        if (mkc || !(sA < 3.4028235e38f)) sA = 3.4028235e38f;

        float x  = -sA;
        float mx = x;
#pragma unroll
        for (int o = 16; o > 0; o >>= 1) mx = fmaxf(mx, __shfl_xor(mx, o, 32));
        float t  = __expf(x - mx) * wc;
        float st = t;
#pragma unroll
        for (int o = 16; o > 0; o >>= 1) st += __shfl_xor(st, o, 32);
        float r = t * __builtin_amdgcn_rcpf(st);

        rbuf[w][l31] = r;

        float o0 = 0.0f, o1 = 0.0f;
#pragma unroll
        for (int q = 0; q < 8; ++q) {
            float4 rv = rb[q];
            half2v h0 = *reinterpret_cast<const half2v*>(&fkw[ROWB * (4 * q + 0) + eaddr[0]]);
            half2v h1 = *reinterpret_cast<const half2v*>(&fkw[ROWB * (4 * q + 1) + eaddr[1]]);
            half2v h2 = *reinterpret_cast<const half2v*>(&fkw[ROWB * (4 * q + 2) + eaddr[2]]);
            half2v h3 = *reinterpret_cast<const half2v*>(&fkw[ROWB * (4 * q + 3) + eaddr[3]]);
            o0 = fmaf(rv.x, (float)h0[0], o0); o1 = fmaf(rv.x, (float)h0[1], o1);
            o0 = fmaf(rv.y, (float)h1[0], o0); o1 = fmaf(rv.y, (float)h1[1], o1);
            o0 = fmaf(rv.z, (float)h2[0], o0); o1 = fmaf(rv.z, (float)h2[1], o1);
            o0 = fmaf(rv.w, (float)h3[0], o0); o1 = fmaf(rv.w, (float)h3[1], o1);
        }
        float2 ov = { o0 + bv.x, o1 + bv.y };
        *reinterpret_cast<float2*>(out + (size_t)nd * DIM + d0) = ov;

        if (!hn) break;
        nd  = ndn;
        mkc = mk_n;
        wc  = mk_n ? 0.0f : tw_n;
#pragma unroll
        for (int i = 0; i < 8; ++i) gb[i] = gb_n[i];
    }
}

extern "C" void kernel_launch(void* const* d_in, const int* in_sizes, int n_in,
                              void* d_out, int out_size, void* d_ws, size_t ws_size,
                              hipStream_t stream) {
    const float* feat = (const float*)d_in[0];
    const float* W    = (const float*)d_in[1];
    const float* bias = (const float*)d_in[2];
    const float* tkw  = (const float*)d_in[3];
    const int*   idx  = (const int*)d_in[4];
    float* out = (float*)d_out;

    const int n = in_sizes[0] / DIM;                       // 50000
    _Float16* hq = (_Float16*)d_ws;                        // n*128*2 = 12.8 MB
    _Float16* wt = hq + (size_t)n * DIM;                   // 32 KB

    // co-resident grid for the cooperative launch (cached occupancy query;
    // host-side only, graph-capture safe)
    static int bpc = 0;
    if (bpc == 0) {
        int v = 0;
        hipError_t e = hipOccupancyMaxActiveBlocksPerMultiprocessor(&v, fused, 192, 0);
        bpc = (e == hipSuccess && v >= 1) ? v : -1;
        if (bpc > 8) bpc = 8;
    }

    bool done = false;
    if (bpc > 0) {
        int grid = bpc * 256;                              // 256 CUs on MI355X
        int nn = n;
        void* args[] = { (void*)&feat, (void*)&W, (void*)&bias, (void*)&tkw,
                         (void*)&idx, (void*)&out, (void*)&hq, (void*)&wt,
                         (void*)&nn };
        hipError_t e = hipLaunchCooperativeKernel(fused, dim3(grid), dim3(192),
                                                  args, 0, stream);
        if (e == hipSuccess) done = true;
        else bpc = -1;                                     // never retry
    }

    if (!done) {
        // fallback: r14 3-kernel path (bit-identical math)
        const int gblocks = (n + 31) / 32;
        const int sblocks = (n + 4 * WPB - 1) / (4 * WPB);
        prep<<<64, 256, 0, stream>>>(W, wt);
        gemm128<<<gblocks, 64, 0, stream>>>(feat, wt, hq, n);
        softk<<<sblocks, 192, 0, stream>>>(hq, bias, tkw, idx, out, n);
    }
}

// Round 6
// 161.276 us; speedup vs baseline: 1.9803x; 1.9803x over previous
//
#include <hip/hip_runtime.h>
#include <math.h>

// SoftKConv, round 19.
// r18 post-mortem: cooperative prep+gemm+softk fusion = 2x REGRESSION
// (fused 312us; MFMA 2%, VALU 9.5%, HBM 11%, WRITE 25->86MB). grid.sync()'s
// device-scope fence invalidates per-XCD L2 -> phase-2 gathers go far-cache;
// abandoned. Byproduct fact: dur_us ~= sum(dispatch)+7us, so in the 3-kernel
// path ~83us of 152.7 is GPU time OUTSIDE softk => gemm128 (1563 single-wave
// blocks = 6.1 waves/CU, latency-starved) is the prime suspect.
// r19: 3-kernel path, softk r14 unchanged; gemm128 re-mapped to 256-thread
// blocks: 4 waves split the 4 independent WT col-tiles of one 32-row tile
// (same grid 1563, 4x waves = 24/CU; per-wave chain 8 MFMAs; feat rows
// shared via L1). Math bit-identical.

typedef __attribute__((ext_vector_type(2)))  _Float16 half2v;
typedef __attribute__((ext_vector_type(4)))  _Float16 half4v;
typedef __attribute__((ext_vector_type(8)))  _Float16 half8;
typedef __attribute__((ext_vector_type(16))) float    f32x16;

#define NK   32
#define DIM  128
// LDS row stride 272 B (64 dwords used + 4 pad); rotation 16*(k&3) dwords.
#define ROWB 272
// waves (independent node streams) per workgroup
#define WPB  3

// ---------------- Kernel 0: WT[n][k] = (f16) W[k][n] -----------------------
__global__ __launch_bounds__(256) void prep(const float* __restrict__ W,
                                            _Float16* __restrict__ WT) {
    int t  = blockIdx.x * 256 + threadIdx.x;   // 0..16383
    int nn = t >> 7, k = t & 127;
    WT[t] = (_Float16)W[k * 128 + nn];
}

// ---------------- Kernel 1: h = feat @ W -> f16, MFMA ----------------------
// 256 threads = 4 waves; wave t computes output cols 32t..32t+31 of the
// block's 32-row tile. 4x wave-parallelism vs r14 (6 -> 24 waves/CU);
// feat loads are identical across the 4 waves (L1-shared).
__global__ __launch_bounds__(256) void gemm128(
    const float* __restrict__ A, const _Float16* __restrict__ WT,
    _Float16* __restrict__ Hq, int n)
{
    const int lane = threadIdx.x & 63;
    const int l31  = lane & 31;
    const int hf   = lane >> 5;
    const int t    = threadIdx.x >> 6;        // col-tile 0..3

    const int row  = blockIdx.x * 32 + l31;
    const int rowc = row < n ? row : n - 1;

    f32x16 acc;
#pragma unroll
    for (int i = 0; i < 16; ++i) acc[i] = 0.0f;

    const float* ap = A + (size_t)rowc * 128 + 8 * hf;
#pragma unroll
    for (int s = 0; s < 8; ++s) {
        float4 b0 = *reinterpret_cast<const float4*>(ap + 16 * s);
        float4 b1 = *reinterpret_cast<const float4*>(ap + 16 * s + 4);
        half8 bf;
        bf[0] = (_Float16)b0.x; bf[1] = (_Float16)b0.y;
        bf[2] = (_Float16)b0.z; bf[3] = (_Float16)b0.w;
        bf[4] = (_Float16)b1.x; bf[5] = (_Float16)b1.y;
        bf[6] = (_Float16)b1.z; bf[7] = (_Float16)b1.w;
        half8 af = *reinterpret_cast<const half8*>(
            WT + (size_t)(l31 + 32 * t) * 128 + 16 * s + 8 * hf);
        acc = __builtin_amdgcn_mfma_f32_32x32x16_f16(af, bf, acc, 0, 0, 0);
    }

    if (row < n) {
        _Float16* hp = Hq + (size_t)row * 128;
#pragma unroll
        for (int g = 0; g < 4; ++g) {
            half4v hv;
#pragma unroll
            for (int q = 0; q < 4; ++q) hv[q] = (_Float16)acc[4 * g + q];
            *reinterpret_cast<half4v*>(hp + 32 * t + 8 * g + 4 * hf) = hv;
        }
    }
}

// ---------------- Kernel 2: per-node soft medoid, pipelined ----------------
// 192 threads = 3 independent waves/block, each wave = its own node stream
// with next-node prefetch. No barriers; per-wave LDS slices are disjoint.
__global__ __launch_bounds__(192, 4) void softk(
    const _Float16* __restrict__ hq, const float* __restrict__ bias,
    const float* __restrict__ tkw, const int* __restrict__ idx,
    float* __restrict__ out, int n)
{
    __shared__ __align__(16) char  fkT[WPB][NK * ROWB];   // 3 x 8704 B
    __shared__ __align__(16) float rbuf[WPB][NK];         // 3 x  128 B

    const int w    = threadIdx.x >> 6;   // wave id in block, 0..2
    const int lane = threadIdx.x & 63;
    const int l31  = lane & 31;
    const int hf   = lane >> 5;
    const int g    = lane >> 4;        // gather row group 0..3
    const int m    = lane & 15;        // gather 16B chunk 0..15
    const int pbase = (lane & 32) + ((lane & 32) >> 3);

    char* fkw = &fkT[w][0];

    // loop-invariant addresses
    const int d0 = 2 * lane;
    const float2 bv = *reinterpret_cast<const float2*>(bias + d0);
    const float4* rb = reinterpret_cast<const float4*>(&rbuf[w][0]);
    // coalesced-write vaddr: row k=4i+g, cols 4m..4m+3 -> 272k + 16*((m+4g)&15)
    const int wbase = ROWB * g + 16 * ((m + 4 * g) & 15);
    // frag-read base (row l31) and rolling rotated column
    const int fbase = ROWB * l31;
    const int uc0   = 4 * hf + 16 * (l31 & 3);       // dword col bias
    // epilogue vaddrs: col lane of row k stored at ((lane + 16*(k&3))&63)
    int eaddr[4];
#pragma unroll
    for (int p = 0; p < 4; ++p) eaddr[p] = 4 * ((lane + 16 * p) & 63);

    const int stride = gridDim.x * WPB;
    int nd = blockIdx.x * WPB + w;
    if (nd >= n) return;

    // ---- prologue: first node's idx/tkw + coalesced gather ----
    int   vid = idx[(size_t)nd * NK + l31];
    float tw  = tkw[(size_t)nd * NK + l31];
    int   mkc = (vid < 0) ? 1 : 0;
    float wc  = mkc ? 0.0f : tw;
    half8 gb[8];
    {
        int idr = mkc ? 0 : vid;                     // per-lane (k=l31) id
#pragma unroll
        for (int i = 0; i < 8; ++i) {
            int idg = __shfl(idr, 4 * i + g, 64);    // row 4i+g's id
            gb[i] = *reinterpret_cast<const half8*>(
                hq + (size_t)idg * DIM + 8 * m);     // lane's 16B of that row
        }
    }

    while (true) {
        const int  ndn = nd + stride;
        const bool hn  = ndn < n;

        // pipeline stage 1: next node's idx/tkw
        int vid_n = 0; float tw_n = 0.0f;
        if (hn) {
            vid_n = idx[(size_t)ndn * NK + l31];
            tw_n  = tkw[(size_t)ndn * NK + l31];
        }

        // ---- coalesced write of gathered rows into rotated LDS ----
#pragma unroll
        for (int i = 0; i < 8; ++i)
            *reinterpret_cast<half8*>(&fkw[1088 * i + wbase]) = gb[i];

        // ---- frag reads (row l31, rotated) + gram MFMA + fdot2 sq ----
        f32x16 acc;
#pragma unroll
        for (int i = 0; i < 16; ++i) acc[i] = 0.0f;
        float sqp = 0.0f;
        int u = uc0;
#pragma unroll
        for (int s = 0; s < 8; ++s) {
            half8 fr = *reinterpret_cast<const half8*>(&fkw[fbase + 4 * (u & 63)]);
            u += 8;
            acc = __builtin_amdgcn_mfma_f32_32x32x16_f16(fr, fr, acc, 0, 0, 0);
            const half2v* p2 = reinterpret_cast<const half2v*>(&fr);
#pragma unroll
            for (int q = 0; q < 4; ++q)
                sqp = __builtin_amdgcn_fdot2(p2[q], p2[q], sqp, false);
        }
        float sq = sqp + __shfl_xor(sqp, 32, 64);

        // pipeline stage 2: next node's coalesced gather (in flight across
        // the dagg/softmax/epilogue tail)
        const int mk_n = (vid_n < 0) ? 1 : 0;
        half8 gb_n[8];
        if (hn) {
            int idr_n = mk_n ? 0 : vid_n;
#pragma unroll
            for (int i = 0; i < 8; ++i) {
                int idg = __shfl(idr_n, 4 * i + g, 64);
                gb_n[i] = *reinterpret_cast<const half8*>(
                    hq + (size_t)idg * DIM + 8 * m);
            }
        }

        // 9th MFMA: acc += -(sq_m + sq_c)/2 -> acc = -d2/2 (hi/lo f16 split)
        {
            _Float16 shi = (_Float16)sq;
            _Float16 slo = (_Float16)(sq - (float)shi);
            _Float16 nh  = (_Float16)(-0.5f * (float)shi);
            _Float16 nl  = (_Float16)(-0.5f * (float)slo);
            _Float16 z   = (_Float16)0.0f, one = (_Float16)1.0f;
            half8 aext = {z, z, z, z, z, z, z, z};
            half8 bext = {z, z, z, z, z, z, z, z};
            if (hf == 0) {
                aext[0] = nh;  aext[1] = nl;  aext[2] = one; aext[3] = one;
                bext[0] = one; bext[1] = one; bext[2] = nh;  bext[3] = nl;
            }
            acc = __builtin_amdgcn_mfma_f32_32x32x16_f16(aext, bext, acc, 0, 0, 0);
        }

        // dagg[c=l31] = sum_m w[m]*dist[m][c]; w[rD] via bpermute; 4-way tree
        float pt[4] = {0.0f, 0.0f, 0.0f, 0.0f};
#pragma unroll
        for (int reg = 0; reg < 16; ++reg) {
            const int c = (reg & 3) + 8 * (reg >> 2);
            float wr = __shfl(wc, pbase + c, 64);        // w[c + 4hf]
            float d2 = fmaxf(-(acc[reg] + acc[reg]), 0.0f);
            float ds = (d2 > 1e-4f) ? __builtin_amdgcn_sqrtf(d2) : 0.0f;
            pt[reg & 3] = fmaf(wr, ds, pt[reg & 3]);
        }
        float part = (pt[0] + pt[1]) + (pt[2] + pt[3]);
        float sA = part + __shfl_xor(part, 32, 64);
        if (mkc || !(sA < 3.4028235e38f)) sA = 3.4028235e38f;

        // fused softmax + weight correction: r = e*w / sum(e*w)
        float x  = -sA;
        float mx = x;
#pragma unroll
        for (int o = 16; o > 0; o >>= 1) mx = fmaxf(mx, __shfl_xor(mx, o, 32));
        float t  = __expf(x - mx) * wc;      // masked lanes: w=0 -> t=0
        float st = t;
#pragma unroll
        for (int o = 16; o > 0; o >>= 1) st += __shfl_xor(st, o, 32);
        float r = t * __builtin_amdgcn_rcpf(st);

        // broadcast r via LDS (dup-write from both halves; benign)
        rbuf[w][l31] = r;

        // ---- epilogue: out[d] = sum_k r_k * fk[k][d]; 2 dims/lane ----
        // lane's dword (cols d0,d0+1) of row k at eaddr[k&3] + 272k (imm).
        float o0 = 0.0f, o1 = 0.0f;
#pragma unroll
        for (int q = 0; q < 8; ++q) {
            float4 rv = rb[q];
            half2v h0 = *reinterpret_cast<const half2v*>(&fkw[ROWB * (4 * q + 0) + eaddr[0]]);
            half2v h1 = *reinterpret_cast<const half2v*>(&fkw[ROWB * (4 * q + 1) + eaddr[1]]);
            half2v h2 = *reinterpret_cast<const half2v*>(&fkw[ROWB * (4 * q + 2) + eaddr[2]]);
            half2v h3 = *reinterpret_cast<const half2v*>(&fkw[ROWB * (4 * q + 3) + eaddr[3]]);
            o0 = fmaf(rv.x, (float)h0[0], o0); o1 = fmaf(rv.x, (float)h0[1], o1);
            o0 = fmaf(rv.y, (float)h1[0], o0); o1 = fmaf(rv.y, (float)h1[1], o1);
            o0 = fmaf(rv.z, (float)h2[0], o0); o1 = fmaf(rv.z, (float)h2[1], o1);
            o0 = fmaf(rv.w, (float)h3[0], o0); o1 = fmaf(rv.w, (float)h3[1], o1);
        }
        float2 ov = { o0 + bv.x, o1 + bv.y };
        *reinterpret_cast<float2*>(out + (size_t)nd * DIM + d0) = ov;

        if (!hn) break;
        // rotate pipeline registers
        nd  = ndn;
        mkc = mk_n;
        wc  = mk_n ? 0.0f : tw_n;
#pragma unroll
        for (int i = 0; i < 8; ++i) gb[i] = gb_n[i];
    }
}

extern "C" void kernel_launch(void* const* d_in, const int* in_sizes, int n_in,
                              void* d_out, int out_size, void* d_ws, size_t ws_size,
                              hipStream_t stream) {
    const float* feat = (const float*)d_in[0];
    const float* W    = (const float*)d_in[1];
    const float* bias = (const float*)d_in[2];
    const float* tkw  = (const float*)d_in[3];
    const int*   idx  = (const int*)d_in[4];
    float* out = (float*)d_out;

    const int n = in_sizes[0] / DIM;                       // 50000
    _Float16* hq = (_Float16*)d_ws;                        // n*128*2 = 12.8 MB
    _Float16* wt = hq + (size_t)n * DIM;                   // 32 KB

    const int gblocks = (n + 31) / 32;                     // 1563 (gemm, 256 thr)
    const int sblocks = (n + 4 * WPB - 1) / (4 * WPB);     // 4167 (softk)

    prep<<<64, 256, 0, stream>>>(W, wt);
    gemm128<<<gblocks, 256, 0, stream>>>(feat, wt, hq, n);
    softk<<<sblocks, 192, 0, stream>>>(hq, bias, tkw, idx, out, n);
}

// Round 7
// 157.047 us; speedup vs baseline: 2.0337x; 1.0269x over previous
//
#include <hip/hip_runtime.h>
#include <math.h>

// SoftKConv, round 20.
// r19 post-mortem: 4x gemm wave-parallelism changed nothing (152.7->161.3,
// softk stable 64us). Roofline math pins gemm <=10us and prep ~1us, so the
// ~90us outside softk is LAUNCH overhead (~25-35us per boundary; r18's
// 1-launch run showed dur ~= dispatch+7us, so fixed cost is small).
// r20: cut 3 launches -> 2. prep is eliminated: each gemm wave builds its
// af fragments directly from W via per-instruction-coalesced strided loads
// (fixed k => 32 consecutive cols = 128B contiguous; W = 64KB, L2-resident).
// Same f32->f16 RNE cast as prep => bit-identical math. softk = r14 exactly.

typedef __attribute__((ext_vector_type(2)))  _Float16 half2v;
typedef __attribute__((ext_vector_type(4)))  _Float16 half4v;
typedef __attribute__((ext_vector_type(8)))  _Float16 half8;
typedef __attribute__((ext_vector_type(16))) float    f32x16;

#define NK   32
#define DIM  128
// LDS row stride 272 B (64 dwords used + 4 pad); rotation 16*(k&3) dwords.
#define ROWB 272
// waves (independent node streams) per workgroup
#define WPB  3

// ---------------- Kernel 1: h = feat @ W -> f16, MFMA ----------------------
// 256 threads = 4 waves; wave t computes output cols 32t..32t+31 of the
// block's 32-row tile. af is loaded straight from W (no prep/WT kernel):
// af[s][e] = (f16) W[16s+8hf+e][col] — per-instruction coalesced (128 B
// contiguous across 32 lanes), W is L2-resident after the first blocks.
__global__ __launch_bounds__(256) void gemm128(
    const float* __restrict__ A, const float* __restrict__ W,
    _Float16* __restrict__ Hq, int n)
{
    const int lane = threadIdx.x & 63;
    const int l31  = lane & 31;
    const int hf   = lane >> 5;
    const int t    = threadIdx.x >> 6;        // col-tile 0..3
    const int col  = l31 + 32 * t;            // output col 0..127

    const int row  = blockIdx.x * 32 + l31;
    const int rowc = row < n ? row : n - 1;

    // ---- af fragments from W (once per wave) ----
    half8 af[8];
#pragma unroll
    for (int s = 0; s < 8; ++s) {
        const float* wp = W + (size_t)(16 * s + 8 * hf) * 128 + col;
#pragma unroll
        for (int e = 0; e < 8; ++e)
            af[s][e] = (_Float16)wp[(size_t)e * 128];
    }

    f32x16 acc;
#pragma unroll
    for (int i = 0; i < 16; ++i) acc[i] = 0.0f;

    const float* ap = A + (size_t)rowc * 128 + 8 * hf;
#pragma unroll
    for (int s = 0; s < 8; ++s) {
        float4 b0 = *reinterpret_cast<const float4*>(ap + 16 * s);
        float4 b1 = *reinterpret_cast<const float4*>(ap + 16 * s + 4);
        half8 bf;
        bf[0] = (_Float16)b0.x; bf[1] = (_Float16)b0.y;
        bf[2] = (_Float16)b0.z; bf[3] = (_Float16)b0.w;
        bf[4] = (_Float16)b1.x; bf[5] = (_Float16)b1.y;
        bf[6] = (_Float16)b1.z; bf[7] = (_Float16)b1.w;
        acc = __builtin_amdgcn_mfma_f32_32x32x16_f16(af[s], bf, acc, 0, 0, 0);
    }

    if (row < n) {
        _Float16* hp = Hq + (size_t)row * 128;
#pragma unroll
        for (int g = 0; g < 4; ++g) {
            half4v hv;
#pragma unroll
            for (int q = 0; q < 4; ++q) hv[q] = (_Float16)acc[4 * g + q];
            *reinterpret_cast<half4v*>(hp + 32 * t + 8 * g + 4 * hf) = hv;
        }
    }
}

// ---------------- Kernel 2: per-node soft medoid, pipelined ----------------
// 192 threads = 3 independent waves/block, each wave = its own node stream
// with next-node prefetch. No barriers; per-wave LDS slices are disjoint.
__global__ __launch_bounds__(192, 4) void softk(
    const _Float16* __restrict__ hq, const float* __restrict__ bias,
    const float* __restrict__ tkw, const int* __restrict__ idx,
    float* __restrict__ out, int n)
{
    __shared__ __align__(16) char  fkT[WPB][NK * ROWB];   // 3 x 8704 B
    __shared__ __align__(16) float rbuf[WPB][NK];         // 3 x  128 B

    const int w    = threadIdx.x >> 6;   // wave id in block, 0..2
    const int lane = threadIdx.x & 63;
    const int l31  = lane & 31;
    const int hf   = lane >> 5;
    const int g    = lane >> 4;        // gather row group 0..3
    const int m    = lane & 15;        // gather 16B chunk 0..15
    const int pbase = (lane & 32) + ((lane & 32) >> 3);

    char* fkw = &fkT[w][0];

    // loop-invariant addresses
    const int d0 = 2 * lane;
    const float2 bv = *reinterpret_cast<const float2*>(bias + d0);
    const float4* rb = reinterpret_cast<const float4*>(&rbuf[w][0]);
    // coalesced-write vaddr: row k=4i+g, cols 4m..4m+3 -> 272k + 16*((m+4g)&15)
    const int wbase = ROWB * g + 16 * ((m + 4 * g) & 15);
    // frag-read base (row l31) and rolling rotated column
    const int fbase = ROWB * l31;
    const int uc0   = 4 * hf + 16 * (l31 & 3);       // dword col bias
    // epilogue vaddrs: col lane of row k stored at ((lane + 16*(k&3))&63)
    int eaddr[4];
#pragma unroll
    for (int p = 0; p < 4; ++p) eaddr[p] = 4 * ((lane + 16 * p) & 63);

    const int stride = gridDim.x * WPB;
    int nd = blockIdx.x * WPB + w;
    if (nd >= n) return;

    // ---- prologue: first node's idx/tkw + coalesced gather ----
    int   vid = idx[(size_t)nd * NK + l31];
    float tw  = tkw[(size_t)nd * NK + l31];
    int   mkc = (vid < 0) ? 1 : 0;
    float wc  = mkc ? 0.0f : tw;
    half8 gb[8];
    {
        int idr = mkc ? 0 : vid;                     // per-lane (k=l31) id
#pragma unroll
        for (int i = 0; i < 8; ++i) {
            int idg = __shfl(idr, 4 * i + g, 64);    // row 4i+g's id
            gb[i] = *reinterpret_cast<const half8*>(
                hq + (size_t)idg * DIM + 8 * m);     // lane's 16B of that row
        }
    }

    while (true) {
        const int  ndn = nd + stride;
        const bool hn  = ndn < n;

        // pipeline stage 1: next node's idx/tkw
        int vid_n = 0; float tw_n = 0.0f;
        if (hn) {
            vid_n = idx[(size_t)ndn * NK + l31];
            tw_n  = tkw[(size_t)ndn * NK + l31];
        }

        // ---- coalesced write of gathered rows into rotated LDS ----
#pragma unroll
        for (int i = 0; i < 8; ++i)
            *reinterpret_cast<half8*>(&fkw[1088 * i + wbase]) = gb[i];

        // ---- frag reads (row l31, rotated) + gram MFMA + fdot2 sq ----
        f32x16 acc;
#pragma unroll
        for (int i = 0; i < 16; ++i) acc[i] = 0.0f;
        float sqp = 0.0f;
        int u = uc0;
#pragma unroll
        for (int s = 0; s < 8; ++s) {
            half8 fr = *reinterpret_cast<const half8*>(&fkw[fbase + 4 * (u & 63)]);
            u += 8;
            acc = __builtin_amdgcn_mfma_f32_32x32x16_f16(fr, fr, acc, 0, 0, 0);
            const half2v* p2 = reinterpret_cast<const half2v*>(&fr);
#pragma unroll
            for (int q = 0; q < 4; ++q)
                sqp = __builtin_amdgcn_fdot2(p2[q], p2[q], sqp, false);
        }
        float sq = sqp + __shfl_xor(sqp, 32, 64);

        // pipeline stage 2: next node's coalesced gather (in flight across
        // the dagg/softmax/epilogue tail)
        const int mk_n = (vid_n < 0) ? 1 : 0;
        half8 gb_n[8];
        if (hn) {
            int idr_n = mk_n ? 0 : vid_n;
#pragma unroll
            for (int i = 0; i < 8; ++i) {
                int idg = __shfl(idr_n, 4 * i + g, 64);
                gb_n[i] = *reinterpret_cast<const half8*>(
                    hq + (size_t)idg * DIM + 8 * m);
            }
        }

        // 9th MFMA: acc += -(sq_m + sq_c)/2 -> acc = -d2/2 (hi/lo f16 split)
        {
            _Float16 shi = (_Float16)sq;
            _Float16 slo = (_Float16)(sq - (float)shi);
            _Float16 nh  = (_Float16)(-0.5f * (float)shi);
            _Float16 nl  = (_Float16)(-0.5f * (float)slo);
            _Float16 z   = (_Float16)0.0f, one = (_Float16)1.0f;
            half8 aext = {z, z, z, z, z, z, z, z};
            half8 bext = {z, z, z, z, z, z, z, z};
            if (hf == 0) {
                aext[0] = nh;  aext[1] = nl;  aext[2] = one; aext[3] = one;
                bext[0] = one; bext[1] = one; bext[2] = nh;  bext[3] = nl;
            }
            acc = __builtin_amdgcn_mfma_f32_32x32x16_f16(aext, bext, acc, 0, 0, 0);
        }

        // dagg[c=l31] = sum_m w[m]*dist[m][c]; w[rD] via bpermute; 4-way tree
        float pt[4] = {0.0f, 0.0f, 0.0f, 0.0f};
#pragma unroll
        for (int reg = 0; reg < 16; ++reg) {
            const int c = (reg & 3) + 8 * (reg >> 2);
            float wr = __shfl(wc, pbase + c, 64);        // w[c + 4hf]
            float d2 = fmaxf(-(acc[reg] + acc[reg]), 0.0f);
            float ds = (d2 > 1e-4f) ? __builtin_amdgcn_sqrtf(d2) : 0.0f;
            pt[reg & 3] = fmaf(wr, ds, pt[reg & 3]);
        }
        float part = (pt[0] + pt[1]) + (pt[2] + pt[3]);
        float sA = part + __shfl_xor(part, 32, 64);
        if (mkc || !(sA < 3.4028235e38f)) sA = 3.4028235e38f;

        // fused softmax + weight correction: r = e*w / sum(e*w)
        float x  = -sA;
        float mx = x;
#pragma unroll
        for (int o = 16; o > 0; o >>= 1) mx = fmaxf(mx, __shfl_xor(mx, o, 32));
        float t  = __expf(x - mx) * wc;      // masked lanes: w=0 -> t=0
        float st = t;
#pragma unroll
        for (int o = 16; o > 0; o >>= 1) st += __shfl_xor(st, o, 32);
        float r = t * __builtin_amdgcn_rcpf(st);

        // broadcast r via LDS (dup-write from both halves; benign)
        rbuf[w][l31] = r;

        // ---- epilogue: out[d] = sum_k r_k * fk[k][d]; 2 dims/lane ----
        // lane's dword (cols d0,d0+1) of row k at eaddr[k&3] + 272k (imm).
        float o0 = 0.0f, o1 = 0.0f;
#pragma unroll
        for (int q = 0; q < 8; ++q) {
            float4 rv = rb[q];
            half2v h0 = *reinterpret_cast<const half2v*>(&fkw[ROWB * (4 * q + 0) + eaddr[0]]);
            half2v h1 = *reinterpret_cast<const half2v*>(&fkw[ROWB * (4 * q + 1) + eaddr[1]]);
            half2v h2 = *reinterpret_cast<const half2v*>(&fkw[ROWB * (4 * q + 2) + eaddr[2]]);
            half2v h3 = *reinterpret_cast<const half2v*>(&fkw[ROWB * (4 * q + 3) + eaddr[3]]);
            o0 = fmaf(rv.x, (float)h0[0], o0); o1 = fmaf(rv.x, (float)h0[1], o1);
            o0 = fmaf(rv.y, (float)h1[0], o0); o1 = fmaf(rv.y, (float)h1[1], o1);
            o0 = fmaf(rv.z, (float)h2[0], o0); o1 = fmaf(rv.z, (float)h2[1], o1);
            o0 = fmaf(rv.w, (float)h3[0], o0); o1 = fmaf(rv.w, (float)h3[1], o1);
        }
        float2 ov = { o0 + bv.x, o1 + bv.y };
        *reinterpret_cast<float2*>(out + (size_t)nd * DIM + d0) = ov;

        if (!hn) break;
        // rotate pipeline registers
        nd  = ndn;
        mkc = mk_n;
        wc  = mk_n ? 0.0f : tw_n;
#pragma unroll
        for (int i = 0; i < 8; ++i) gb[i] = gb_n[i];
    }
}

extern "C" void kernel_launch(void* const* d_in, const int* in_sizes, int n_in,
                              void* d_out, int out_size, void* d_ws, size_t ws_size,
                              hipStream_t stream) {
    const float* feat = (const float*)d_in[0];
    const float* W    = (const float*)d_in[1];
    const float* bias = (const float*)d_in[2];
    const float* tkw  = (const float*)d_in[3];
    const int*   idx  = (const int*)d_in[4];
    float* out = (float*)d_out;

    const int n = in_sizes[0] / DIM;                       // 50000
    _Float16* hq = (_Float16*)d_ws;                        // n*128*2 = 12.8 MB

    const int gblocks = (n + 31) / 32;                     // 1563 (gemm, 256 thr)
    const int sblocks = (n + 4 * WPB - 1) / (4 * WPB);     // 4167 (softk)

    gemm128<<<gblocks, 256, 0, stream>>>(feat, W, hq, n);
    softk<<<sblocks, 192, 0, stream>>>(hq, bias, tkw, idx, out, n);
}

// Round 11
// 146.772 us; speedup vs baseline: 2.1760x; 1.0700x over previous
//
#include <hip/hip_runtime.h>
#include <math.h>

// SoftKConv, round 24 (= r21/r22/r23 resubmitted; all prior benches died on
// GPU acquisition timeout — no data, kernel untested on HW).
// r20 post-mortem: removing prep launch changed nothing (157.0us) => launch
// boundaries are cheap. gemm absent from top-5 (<65us) but ~92us remains
// outside softk. r19's 4x-wave gemm null result => gemm is THROUGHPUT-bound,
// not latency-bound: its feat loads / Hq stores scatter 64 lanes across 32
// rows (512B apart) per instruction => ~2-3K coalescer transactions per wave,
// invariant under all prior reorganizations. r21..r24: LDS-staged gemm —
// coalesced 128B global loads -> LDS -> per-lane fragment reads; output
// staged through LDS -> contiguous row stores. ~30x fewer transactions.
// Same f32->f16 RNE casts, same MFMA order => bit-identical. softk = r14.

typedef __attribute__((ext_vector_type(2)))  _Float16 half2v;
typedef __attribute__((ext_vector_type(4)))  _Float16 half4v;
typedef __attribute__((ext_vector_type(8)))  _Float16 half8;
typedef __attribute__((ext_vector_type(16))) float    f32x16;

#define NK   32
#define DIM  128
// softk LDS row stride 272 B (64 dwords used + 4 pad); rotation 16*(k&3) dwords.
#define ROWB 272
// waves (independent node streams) per softk workgroup
#define WPB  3

// ---------------- Kernel 1: h = feat @ W -> f16, MFMA, LDS-staged ----------
// 256 threads = 4 waves; wave t computes output cols 32t..32t+31 of the
// block's 32-row tile. feat tile staged via LDS (coalesced both ways).
// af loaded straight from W (L2-resident, 2 txns/instr).
__global__ __launch_bounds__(256) void gemm128(
    const float* __restrict__ A, const float* __restrict__ W,
    _Float16* __restrict__ Hq, int n)
{
    // 32 rows x 132 floats (528 B stride: 16B-aligned, pad kills pow2 stride)
    __shared__ __align__(16) char smem[32 * 528];          // 16896 B

    const int tid  = threadIdx.x;
    const int lane = tid & 63;
    const int l31  = lane & 31;
    const int hf   = lane >> 5;
    const int t    = tid >> 6;                // col-tile 0..3
    const int col  = l31 + 32 * t;            // output col 0..127

    const int row0 = blockIdx.x * 32;

    // ---- stage feat tile: fully coalesced (8 threads/row, 128B runs) ----
    {
        const int r = tid >> 3;               // 0..31
        const int c = tid & 7;                // 16B chunk group
        int rr = row0 + r; if (rr >= n) rr = n - 1;
        const float* src = A + (size_t)rr * 128 + 4 * c;
        char* dst = smem + r * 528 + 16 * c;
#pragma unroll
        for (int i = 0; i < 4; ++i) {
            float4 v = *reinterpret_cast<const float4*>(src + 32 * i);
            *reinterpret_cast<float4*>(dst + 128 * i) = v;
        }
    }

    // ---- af fragments from W (once per wave; 2 txns/instr, L2-hot) ----
    half8 af[8];
#pragma unroll
    for (int s = 0; s < 8; ++s) {
        const float* wp = W + (size_t)(16 * s + 8 * hf) * 128 + col;
#pragma unroll
        for (int e = 0; e < 8; ++e)
            af[s][e] = (_Float16)wp[(size_t)e * 128];
    }

    __syncthreads();

    // ---- bf from LDS (row l31, 16B-aligned) + MFMA ----
    f32x16 acc;
#pragma unroll
    for (int i = 0; i < 16; ++i) acc[i] = 0.0f;

    const char* myrow = smem + l31 * 528 + 32 * hf;        // float col 8*hf
#pragma unroll
    for (int s = 0; s < 8; ++s) {
        float4 b0 = *reinterpret_cast<const float4*>(myrow + 64 * s);
        float4 b1 = *reinterpret_cast<const float4*>(myrow + 64 * s + 16);
        half8 bf;
        bf[0] = (_Float16)b0.x; bf[1] = (_Float16)b0.y;
        bf[2] = (_Float16)b0.z; bf[3] = (_Float16)b0.w;
        bf[4] = (_Float16)b1.x; bf[5] = (_Float16)b1.y;
        bf[6] = (_Float16)b1.z; bf[7] = (_Float16)b1.w;
        acc = __builtin_amdgcn_mfma_f32_32x32x16_f16(af[s], bf, acc, 0, 0, 0);
    }

    __syncthreads();                                       // done reading tile

    // ---- stage output f16 tile in LDS (32 rows x 272 B stride) ----
    {
        char* orow = smem + l31 * 272 + 64 * t + 8 * hf;   // half col 32t+4hf
#pragma unroll
        for (int g = 0; g < 4; ++g) {
            half4v hv;
#pragma unroll
            for (int q = 0; q < 4; ++q) hv[q] = (_Float16)acc[4 * g + q];
            *reinterpret_cast<half4v*>(orow + 16 * g) = hv;
        }
    }

    __syncthreads();

    // ---- coalesced row stores: 8 threads/row, 16B each, 2 iters ----
    {
        const int r = tid >> 3;
        const int c = tid & 7;
        const int orow = row0 + r;
        if (orow < n) {
            const char* srcl = smem + r * 272 + 16 * c;
            _Float16*   dst  = Hq + (size_t)orow * 128 + 8 * c;
#pragma unroll
            for (int i = 0; i < 2; ++i) {
                half8 v = *reinterpret_cast<const half8*>(srcl + 128 * i);
                *reinterpret_cast<half8*>(dst + 64 * i) = v;
            }
        }
    }
}

// ---------------- Kernel 2: per-node soft medoid, pipelined ----------------
// 192 threads = 3 independent waves/block, each wave = its own node stream
// with next-node prefetch. No barriers; per-wave LDS slices are disjoint.
__global__ __launch_bounds__(192, 4) void softk(
    const _Float16* __restrict__ hq, const float* __restrict__ bias,
    const float* __restrict__ tkw, const int* __restrict__ idx,
    float* __restrict__ out, int n)
{
    __shared__ __align__(16) char  fkT[WPB][NK * ROWB];   // 3 x 8704 B
    __shared__ __align__(16) float rbuf[WPB][NK];         // 3 x  128 B

    const int w    = threadIdx.x >> 6;   // wave id in block, 0..2
    const int lane = threadIdx.x & 63;
    const int l31  = lane & 31;
    const int hf   = lane >> 5;
    const int g    = lane >> 4;        // gather row group 0..3
    const int m    = lane & 15;        // gather 16B chunk 0..15
    const int pbase = (lane & 32) + ((lane & 32) >> 3);

    char* fkw = &fkT[w][0];

    // loop-invariant addresses
    const int d0 = 2 * lane;
    const float2 bv = *reinterpret_cast<const float2*>(bias + d0);
    const float4* rb = reinterpret_cast<const float4*>(&rbuf[w][0]);
    // coalesced-write vaddr: row k=4i+g, cols 4m..4m+3 -> 272k + 16*((m+4g)&15)
    const int wbase = ROWB * g + 16 * ((m + 4 * g) & 15);
    // frag-read base (row l31) and rolling rotated column
    const int fbase = ROWB * l31;
    const int uc0   = 4 * hf + 16 * (l31 & 3);       // dword col bias
    // epilogue vaddrs: col lane of row k stored at ((lane + 16*(k&3))&63)
    int eaddr[4];
#pragma unroll
    for (int p = 0; p < 4; ++p) eaddr[p] = 4 * ((lane + 16 * p) & 63);

    const int stride = gridDim.x * WPB;
    int nd = blockIdx.x * WPB + w;
    if (nd >= n) return;

    // ---- prologue: first node's idx/tkw + coalesced gather ----
    int   vid = idx[(size_t)nd * NK + l31];
    float tw  = tkw[(size_t)nd * NK + l31];
    int   mkc = (vid < 0) ? 1 : 0;
    float wc  = mkc ? 0.0f : tw;
    half8 gb[8];
    {
        int idr = mkc ? 0 : vid;                     // per-lane (k=l31) id
#pragma unroll
        for (int i = 0; i < 8; ++i) {
            int idg = __shfl(idr, 4 * i + g, 64);    // row 4i+g's id
            gb[i] = *reinterpret_cast<const half8*>(
                hq + (size_t)idg * DIM + 8 * m);     // lane's 16B of that row
        }
    }

    while (true) {
        const int  ndn = nd + stride;
        const bool hn  = ndn < n;

        // pipeline stage 1: next node's idx/tkw
        int vid_n = 0; float tw_n = 0.0f;
        if (hn) {
            vid_n = idx[(size_t)ndn * NK + l31];
            tw_n  = tkw[(size_t)ndn * NK + l31];
        }

        // ---- coalesced write of gathered rows into rotated LDS ----
#pragma unroll
        for (int i = 0; i < 8; ++i)
            *reinterpret_cast<half8*>(&fkw[1088 * i + wbase]) = gb[i];

        // ---- frag reads (row l31, rotated) + gram MFMA + fdot2 sq ----
        f32x16 acc;
#pragma unroll
        for (int i = 0; i < 16; ++i) acc[i] = 0.0f;
        float sqp = 0.0f;
        int u = uc0;
#pragma unroll
        for (int s = 0; s < 8; ++s) {
            half8 fr = *reinterpret_cast<const half8*>(&fkw[fbase + 4 * (u & 63)]);
            u += 8;
            acc = __builtin_amdgcn_mfma_f32_32x32x16_f16(fr, fr, acc, 0, 0, 0);
            const half2v* p2 = reinterpret_cast<const half2v*>(&fr);
#pragma unroll
            for (int q = 0; q < 4; ++q)
                sqp = __builtin_amdgcn_fdot2(p2[q], p2[q], sqp, false);
        }
        float sq = sqp + __shfl_xor(sqp, 32, 64);

        // pipeline stage 2: next node's coalesced gather (in flight across
        // the dagg/softmax/epilogue tail)
        const int mk_n = (vid_n < 0) ? 1 : 0;
        half8 gb_n[8];
        if (hn) {
            int idr_n = mk_n ? 0 : vid_n;
#pragma unroll
            for (int i = 0; i < 8; ++i) {
                int idg = __shfl(idr_n, 4 * i + g, 64);
                gb_n[i] = *reinterpret_cast<const half8*>(
                    hq + (size_t)idg * DIM + 8 * m);
            }
        }

        // 9th MFMA: acc += -(sq_m + sq_c)/2 -> acc = -d2/2 (hi/lo f16 split)
        {
            _Float16 shi = (_Float16)sq;
            _Float16 slo = (_Float16)(sq - (float)shi);
            _Float16 nh  = (_Float16)(-0.5f * (float)shi);
            _Float16 nl  = (_Float16)(-0.5f * (float)slo);
            _Float16 z   = (_Float16)0.0f, one = (_Float16)1.0f;
            half8 aext = {z, z, z, z, z, z, z, z};
            half8 bext = {z, z, z, z, z, z, z, z};
            if (hf == 0) {
                aext[0] = nh;  aext[1] = nl;  aext[2] = one; aext[3] = one;
                bext[0] = one; bext[1] = one; bext[2] = nh;  bext[3] = nl;
            }
            acc = __builtin_amdgcn_mfma_f32_32x32x16_f16(aext, bext, acc, 0, 0, 0);
        }

        // dagg[c=l31] = sum_m w[m]*dist[m][c]; w[rD] via bpermute; 4-way tree
        float pt[4] = {0.0f, 0.0f, 0.0f, 0.0f};
#pragma unroll
        for (int reg = 0; reg < 16; ++reg) {
            const int c = (reg & 3) + 8 * (reg >> 2);
            float wr = __shfl(wc, pbase + c, 64);        // w[c + 4hf]
            float d2 = fmaxf(-(acc[reg] + acc[reg]), 0.0f);
            float ds = (d2 > 1e-4f) ? __builtin_amdgcn_sqrtf(d2) : 0.0f;
            pt[reg & 3] = fmaf(wr, ds, pt[reg & 3]);
        }
        float part = (pt[0] + pt[1]) + (pt[2] + pt[3]);
        float sA = part + __shfl_xor(part, 32, 64);
        if (mkc || !(sA < 3.4028235e38f)) sA = 3.4028235e38f;

        // fused softmax + weight correction: r = e*w / sum(e*w)
        float x  = -sA;
        float mx = x;
#pragma unroll
        for (int o = 16; o > 0; o >>= 1) mx = fmaxf(mx, __shfl_xor(mx, o, 32));
        float t  = __expf(x - mx) * wc;      // masked lanes: w=0 -> t=0
        float st = t;
#pragma unroll
        for (int o = 16; o > 0; o >>= 1) st += __shfl_xor(st, o, 32);
        float r = t * __builtin_amdgcn_rcpf(st);

        // broadcast r via LDS (dup-write from both halves; benign)
        rbuf[w][l31] = r;

        // ---- epilogue: out[d] = sum_k r_k * fk[k][d]; 2 dims/lane ----
        // lane's dword (cols d0,d0+1) of row k at eaddr[k&3] + 272k (imm).
        float o0 = 0.0f, o1 = 0.0f;
#pragma unroll
        for (int q = 0; q < 8; ++q) {
            float4 rv = rb[q];
            half2v h0 = *reinterpret_cast<const half2v*>(&fkw[ROWB * (4 * q + 0) + eaddr[0]]);
            half2v h1 = *reinterpret_cast<const half2v*>(&fkw[ROWB * (4 * q + 1) + eaddr[1]]);
            half2v h2 = *reinterpret_cast<const half2v*>(&fkw[ROWB * (4 * q + 2) + eaddr[2]]);
            half2v h3 = *reinterpret_cast<const half2v*>(&fkw[ROWB * (4 * q + 3) + eaddr[3]]);
            o0 = fmaf(rv.x, (float)h0[0], o0); o1 = fmaf(rv.x, (float)h0[1], o1);
            o0 = fmaf(rv.y, (float)h1[0], o0); o1 = fmaf(rv.y, (float)h1[1], o1);
            o0 = fmaf(rv.z, (float)h2[0], o0); o1 = fmaf(rv.z, (float)h2[1], o1);
            o0 = fmaf(rv.w, (float)h3[0], o0); o1 = fmaf(rv.w, (float)h3[1], o1);
        }
        float2 ov = { o0 + bv.x, o1 + bv.y };
        *reinterpret_cast<float2*>(out + (size_t)nd * DIM + d0) = ov;

        if (!hn) break;
        // rotate pipeline registers
        nd  = ndn;
        mkc = mk_n;
        wc  = mk_n ? 0.0f : tw_n;
#pragma unroll
        for (int i = 0; i < 8; ++i) gb[i] = gb_n[i];
    }
}

extern "C" void kernel_launch(void* const* d_in, const int* in_sizes, int n_in,
                              void* d_out, int out_size, void* d_ws, size_t ws_size,
                              hipStream_t stream) {
    const float* feat = (const float*)d_in[0];
    const float* W    = (const float*)d_in[1];
    const float* bias = (const float*)d_in[2];
    const float* tkw  = (const float*)d_in[3];
    const int*   idx  = (const int*)d_in[4];
    float* out = (float*)d_out;

    const int n = in_sizes[0] / DIM;                       // 50000
    _Float16* hq = (_Float16*)d_ws;                        // n*128*2 = 12.8 MB

    const int gblocks = (n + 31) / 32;                     // 1563 (gemm, 256 thr)
    const int sblocks = (n + 4 * WPB - 1) / (4 * WPB);     // 4167 (softk)

    gemm128<<<gblocks, 256, 0, stream>>>(feat, W, hq, n);
    softk<<<sblocks, 192, 0, stream>>>(hq, bias, tkw, idx, out, n);
}

// Round 14
// 145.877 us; speedup vs baseline: 2.1894x; 1.0061x over previous
//
#include <hip/hip_runtime.h>
#include <math.h>

// SoftKConv, round 27 (= r25/r26 resubmitted; both prior benches died on
// GPU acquisition timeout — no data, kernel untested on HW).
// r21 post-mortem (ran as r24): LDS-staged gemm = NEW BEST 146.8us (-10 vs
// r20). softk pinned at ~64.8us, FETCH 149.7MB = fabric-bound random gather
// (L2-hit ~64% model checks out) — softk is at its floor. Accounting across
// all rounds forces gemm ~ 55-64us (just under the top-5 cutoff) despite a
// <=10us roofline — a per-BLOCK cost, invariant under 3 rewrites.
// r25..r27: persistent gemm. 512 blocks x ~3 tiles, af W-fragments hoisted
// and loaded ONCE per block (3x less W traffic; per-tile body = stage feat
// -> MFMA -> stage out -> store). Same casts, same MFMA order =>
// bit-identical. softk = r14 exactly.

typedef __attribute__((ext_vector_type(2)))  _Float16 half2v;
typedef __attribute__((ext_vector_type(4)))  _Float16 half4v;
typedef __attribute__((ext_vector_type(8)))  _Float16 half8;
typedef __attribute__((ext_vector_type(16))) float    f32x16;

#define NK   32
#define DIM  128
// softk LDS row stride 272 B (64 dwords used + 4 pad); rotation 16*(k&3) dwords.
#define ROWB 272
// waves (independent node streams) per softk workgroup
#define WPB  3
// persistent gemm grid
#define GEMM_BLOCKS 512

// ---------------- Kernel 1: h = feat @ W -> f16, persistent MFMA -----------
// 256 threads = 4 waves; wave t owns output cols 32t..32t+31. Each block
// grid-strides over 32-row tiles; af (W fragments) loaded once per block.
__global__ __launch_bounds__(256) void gemm128(
    const float* __restrict__ A, const float* __restrict__ W,
    _Float16* __restrict__ Hq, int n)
{
    // 32 rows x 132 floats (528 B stride: 16B-aligned, pad kills pow2 stride)
    __shared__ __align__(16) char smem[32 * 528];          // 16896 B

    const int tid  = threadIdx.x;
    const int lane = tid & 63;
    const int l31  = lane & 31;
    const int hf   = lane >> 5;
    const int t    = tid >> 6;                // col-tile 0..3
    const int col  = l31 + 32 * t;            // output col 0..127

    // staging thread mapping (8 threads/row)
    const int sr = tid >> 3;                  // 0..31
    const int sc = tid & 7;                   // 16B chunk group

    // ---- af fragments from W: ONCE per block (amortized over tiles) ----
    half8 af[8];
#pragma unroll
    for (int s = 0; s < 8; ++s) {
        const float* wp = W + (size_t)(16 * s + 8 * hf) * 128 + col;
#pragma unroll
        for (int e = 0; e < 8; ++e)
            af[s][e] = (_Float16)wp[(size_t)e * 128];
    }

    const int ntiles = (n + 31) >> 5;
    for (int tile = blockIdx.x; tile < ntiles; tile += GEMM_BLOCKS) {
        const int row0 = tile * 32;

        __syncthreads();   // prior iteration's smem readers done

        // ---- stage feat tile: fully coalesced (8 threads/row, 128B runs) --
        {
            int rr = row0 + sr; if (rr >= n) rr = n - 1;
            const float* src = A + (size_t)rr * 128 + 4 * sc;
            char* dst = smem + sr * 528 + 16 * sc;
#pragma unroll
            for (int i = 0; i < 4; ++i) {
                float4 v = *reinterpret_cast<const float4*>(src + 32 * i);
                *reinterpret_cast<float4*>(dst + 128 * i) = v;
            }
        }

        __syncthreads();

        // ---- bf from LDS (row l31, 16B-aligned) + MFMA ----
        f32x16 acc;
#pragma unroll
        for (int i = 0; i < 16; ++i) acc[i] = 0.0f;

        const char* myrow = smem + l31 * 528 + 32 * hf;    // float col 8*hf
#pragma unroll
        for (int s = 0; s < 8; ++s) {
            float4 b0 = *reinterpret_cast<const float4*>(myrow + 64 * s);
            float4 b1 = *reinterpret_cast<const float4*>(myrow + 64 * s + 16);
            half8 bf;
            bf[0] = (_Float16)b0.x; bf[1] = (_Float16)b0.y;
            bf[2] = (_Float16)b0.z; bf[3] = (_Float16)b0.w;
            bf[4] = (_Float16)b1.x; bf[5] = (_Float16)b1.y;
            bf[6] = (_Float16)b1.z; bf[7] = (_Float16)b1.w;
            acc = __builtin_amdgcn_mfma_f32_32x32x16_f16(af[s], bf, acc, 0, 0, 0);
        }

        __syncthreads();                                   // done reading tile

        // ---- stage output f16 tile in LDS (32 rows x 272 B stride) ----
        {
            char* orow = smem + l31 * 272 + 64 * t + 8 * hf;
#pragma unroll
            for (int g = 0; g < 4; ++g) {
                half4v hv;
#pragma unroll
                for (int q = 0; q < 4; ++q) hv[q] = (_Float16)acc[4 * g + q];
                *reinterpret_cast<half4v*>(orow + 16 * g) = hv;
            }
        }

        __syncthreads();

        // ---- coalesced row stores: 8 threads/row, 16B each, 2 iters ----
        {
            const int orow = row0 + sr;
            if (orow < n) {
                const char* srcl = smem + sr * 272 + 16 * sc;
                _Float16*   dst  = Hq + (size_t)orow * 128 + 8 * sc;
#pragma unroll
                for (int i = 0; i < 2; ++i) {
                    half8 v = *reinterpret_cast<const half8*>(srcl + 128 * i);
                    *reinterpret_cast<half8*>(dst + 64 * i) = v;
                }
            }
        }
    }
}

// ---------------- Kernel 2: per-node soft medoid, pipelined ----------------
// 192 threads = 3 independent waves/block, each wave = its own node stream
// with next-node prefetch. No barriers; per-wave LDS slices are disjoint.
__global__ __launch_bounds__(192, 4) void softk(
    const _Float16* __restrict__ hq, const float* __restrict__ bias,
    const float* __restrict__ tkw, const int* __restrict__ idx,
    float* __restrict__ out, int n)
{
    __shared__ __align__(16) char  fkT[WPB][NK * ROWB];   // 3 x 8704 B
    __shared__ __align__(16) float rbuf[WPB][NK];         // 3 x  128 B

    const int w    = threadIdx.x >> 6;   // wave id in block, 0..2
    const int lane = threadIdx.x & 63;
    const int l31  = lane & 31;
    const int hf   = lane >> 5;
    const int g    = lane >> 4;        // gather row group 0..3
    const int m    = lane & 15;        // gather 16B chunk 0..15
    const int pbase = (lane & 32) + ((lane & 32) >> 3);

    char* fkw = &fkT[w][0];

    // loop-invariant addresses
    const int d0 = 2 * lane;
    const float2 bv = *reinterpret_cast<const float2*>(bias + d0);
    const float4* rb = reinterpret_cast<const float4*>(&rbuf[w][0]);
    // coalesced-write vaddr: row k=4i+g, cols 4m..4m+3 -> 272k + 16*((m+4g)&15)
    const int wbase = ROWB * g + 16 * ((m + 4 * g) & 15);
    // frag-read base (row l31) and rolling rotated column
    const int fbase = ROWB * l31;
    const int uc0   = 4 * hf + 16 * (l31 & 3);       // dword col bias
    // epilogue vaddrs: col lane of row k stored at ((lane + 16*(k&3))&63)
    int eaddr[4];
#pragma unroll
    for (int p = 0; p < 4; ++p) eaddr[p] = 4 * ((lane + 16 * p) & 63);

    const int stride = gridDim.x * WPB;
    int nd = blockIdx.x * WPB + w;
    if (nd >= n) return;

    // ---- prologue: first node's idx/tkw + coalesced gather ----
    int   vid = idx[(size_t)nd * NK + l31];
    float tw  = tkw[(size_t)nd * NK + l31];
    int   mkc = (vid < 0) ? 1 : 0;
    float wc  = mkc ? 0.0f : tw;
    half8 gb[8];
    {
        int idr = mkc ? 0 : vid;                     // per-lane (k=l31) id
#pragma unroll
        for (int i = 0; i < 8; ++i) {
            int idg = __shfl(idr, 4 * i + g, 64);    // row 4i+g's id
            gb[i] = *reinterpret_cast<const half8*>(
                hq + (size_t)idg * DIM + 8 * m);     // lane's 16B of that row
        }
    }

    while (true) {
        const int  ndn = nd + stride;
        const bool hn  = ndn < n;

        // pipeline stage 1: next node's idx/tkw
        int vid_n = 0; float tw_n = 0.0f;
        if (hn) {
            vid_n = idx[(size_t)ndn * NK + l31];
            tw_n  = tkw[(size_t)ndn * NK + l31];
        }

        // ---- coalesced write of gathered rows into rotated LDS ----
#pragma unroll
        for (int i = 0; i < 8; ++i)
            *reinterpret_cast<half8*>(&fkw[1088 * i + wbase]) = gb[i];

        // ---- frag reads (row l31, rotated) + gram MFMA + fdot2 sq ----
        f32x16 acc;
#pragma unroll
        for (int i = 0; i < 16; ++i) acc[i] = 0.0f;
        float sqp = 0.0f;
        int u = uc0;
#pragma unroll
        for (int s = 0; s < 8; ++s) {
            half8 fr = *reinterpret_cast<const half8*>(&fkw[fbase + 4 * (u & 63)]);
            u += 8;
            acc = __builtin_amdgcn_mfma_f32_32x32x16_f16(fr, fr, acc, 0, 0, 0);
            const half2v* p2 = reinterpret_cast<const half2v*>(&fr);
#pragma unroll
            for (int q = 0; q < 4; ++q)
                sqp = __builtin_amdgcn_fdot2(p2[q], p2[q], sqp, false);
        }
        float sq = sqp + __shfl_xor(sqp, 32, 64);

        // pipeline stage 2: next node's coalesced gather (in flight across
        // the dagg/softmax/epilogue tail)
        const int mk_n = (vid_n < 0) ? 1 : 0;
        half8 gb_n[8];
        if (hn) {
            int idr_n = mk_n ? 0 : vid_n;
#pragma unroll
            for (int i = 0; i < 8; ++i) {
                int idg = __shfl(idr_n, 4 * i + g, 64);
                gb_n[i] = *reinterpret_cast<const half8*>(
                    hq + (size_t)idg * DIM + 8 * m);
            }
        }

        // 9th MFMA: acc += -(sq_m + sq_c)/2 -> acc = -d2/2 (hi/lo f16 split)
        {
            _Float16 shi = (_Float16)sq;
            _Float16 slo = (_Float16)(sq - (float)shi);
            _Float16 nh  = (_Float16)(-0.5f * (float)shi);
            _Float16 nl  = (_Float16)(-0.5f * (float)slo);
            _Float16 z   = (_Float16)0.0f, one = (_Float16)1.0f;
            half8 aext = {z, z, z, z, z, z, z, z};
            half8 bext = {z, z, z, z, z, z, z, z};
            if (hf == 0) {
                aext[0] = nh;  aext[1] = nl;  aext[2] = one; aext[3] = one;
                bext[0] = one; bext[1] = one; bext[2] = nh;  bext[3] = nl;
            }
            acc = __builtin_amdgcn_mfma_f32_32x32x16_f16(aext, bext, acc, 0, 0, 0);
        }

        // dagg[c=l31] = sum_m w[m]*dist[m][c]; w[rD] via bpermute; 4-way tree
        float pt[4] = {0.0f, 0.0f, 0.0f, 0.0f};
#pragma unroll
        for (int reg = 0; reg < 16; ++reg) {
            const int c = (reg & 3) + 8 * (reg >> 2);
            float wr = __shfl(wc, pbase + c, 64);        // w[c + 4hf]
            float d2 = fmaxf(-(acc[reg] + acc[reg]), 0.0f);
            float ds = (d2 > 1e-4f) ? __builtin_amdgcn_sqrtf(d2) : 0.0f;
            pt[reg & 3] = fmaf(wr, ds, pt[reg & 3]);
        }
        float part = (pt[0] + pt[1]) + (pt[2] + pt[3]);
        float sA = part + __shfl_xor(part, 32, 64);
        if (mkc || !(sA < 3.4028235e38f)) sA = 3.4028235e38f;

        // fused softmax + weight correction: r = e*w / sum(e*w)
        float x  = -sA;
        float mx = x;
#pragma unroll
        for (int o = 16; o > 0; o >>= 1) mx = fmaxf(mx, __shfl_xor(mx, o, 32));
        float t  = __expf(x - mx) * wc;      // masked lanes: w=0 -> t=0
        float st = t;
#pragma unroll
        for (int o = 16; o > 0; o >>= 1) st += __shfl_xor(st, o, 32);
        float r = t * __builtin_amdgcn_rcpf(st);

        // broadcast r via LDS (dup-write from both halves; benign)
        rbuf[w][l31] = r;

        // ---- epilogue: out[d] = sum_k r_k * fk[k][d]; 2 dims/lane ----
        // lane's dword (cols d0,d0+1) of row k at eaddr[k&3] + 272k (imm).
        float o0 = 0.0f, o1 = 0.0f;
#pragma unroll
        for (int q = 0; q < 8; ++q) {
            float4 rv = rb[q];
            half2v h0 = *reinterpret_cast<const half2v*>(&fkw[ROWB * (4 * q + 0) + eaddr[0]]);
            half2v h1 = *reinterpret_cast<const half2v*>(&fkw[ROWB * (4 * q + 1) + eaddr[1]]);
            half2v h2 = *reinterpret_cast<const half2v*>(&fkw[ROWB * (4 * q + 2) + eaddr[2]]);
            half2v h3 = *reinterpret_cast<const half2v*>(&fkw[ROWB * (4 * q + 3) + eaddr[3]]);
            o0 = fmaf(rv.x, (float)h0[0], o0); o1 = fmaf(rv.x, (float)h0[1], o1);
            o0 = fmaf(rv.y, (float)h1[0], o0); o1 = fmaf(rv.y, (float)h1[1], o1);
            o0 = fmaf(rv.z, (float)h2[0], o0); o1 = fmaf(rv.z, (float)h2[1], o1);
            o0 = fmaf(rv.w, (float)h3[0], o0); o1 = fmaf(rv.w, (float)h3[1], o1);
        }
        float2 ov = { o0 + bv.x, o1 + bv.y };
        *reinterpret_cast<float2*>(out + (size_t)nd * DIM + d0) = ov;

        if (!hn) break;
        // rotate pipeline registers
        nd  = ndn;
        mkc = mk_n;
        wc  = mk_n ? 0.0f : tw_n;
#pragma unroll
        for (int i = 0; i < 8; ++i) gb[i] = gb_n[i];
    }
}

extern "C" void kernel_launch(void* const* d_in, const int* in_sizes, int n_in,
                              void* d_out, int out_size, void* d_ws, size_t ws_size,
                              hipStream_t stream) {
    const float* feat = (const float*)d_in[0];
    const float* W    = (const float*)d_in[1];
    const float* bias = (const float*)d_in[2];
    const float* tkw  = (const float*)d_in[3];
    const int*   idx  = (const int*)d_in[4];
    float* out = (float*)d_out;

    const int n = in_sizes[0] / DIM;                       // 50000
    _Float16* hq = (_Float16*)d_ws;                        // n*128*2 = 12.8 MB

    const int sblocks = (n + 4 * WPB - 1) / (4 * WPB);     // 4167 (softk)

    gemm128<<<GEMM_BLOCKS, 256, 0, stream>>>(feat, W, hq, n);
    softk<<<sblocks, 192, 0, stream>>>(hq, bias, tkw, idx, out, n);
}